// Round 3
// baseline (273.689 us; speedup 1.0000x reference)
//
#include <hip/hip_runtime.h>
#include <hip/hip_bf16.h>
#include <cstdint>

#define BATCH 32
#define NKEY 2048
#define DIM 256
#define NHEAD 8
#define SEEDS 32
#define DHEAD 32
#define SCALE 0.0625f
#define NCHUNK 16
#define CHUNK 128
#define PART_STRIDE 8448  // 8192 numer + 256 denom floats per (b,chunk)

typedef unsigned short u16;
typedef __attribute__((ext_vector_type(8))) short s16x8;
typedef __attribute__((ext_vector_type(8))) unsigned short u16x8;
typedef __attribute__((ext_vector_type(4))) float f32x4;

__device__ __forceinline__ u16 f2bf(float f) {
    unsigned u = __float_as_uint(f);
    u += 0x7FFFu + ((u >> 16) & 1u);
    return (u16)(u >> 16);
}
__device__ __forceinline__ float bf2f(u16 h) {
    return __uint_as_float(((unsigned)h) << 16);
}
// lengths may arrive as int32 or raw int64; lengths>=1 so int64 layout has lens[1]==0
__device__ __forceinline__ int get_len(const int* lens, int b) {
    return (lens[1] == 0) ? lens[2 * b] : lens[b];
}

// ---------------- Kernel 1: Q = S @ Wq^T  (32 x 256) ----------------
__global__ __launch_bounds__(256) void qproj_kernel(const float* __restrict__ S,
                                                    const float* __restrict__ Wq,
                                                    float* __restrict__ qf) {
    int s = blockIdx.x;      // seed
    int e = threadIdx.x;     // out channel
    __shared__ float srow[DIM];
    srow[e] = S[s * DIM + e];
    __syncthreads();
    const float* wr = Wq + (size_t)e * DIM;
    float acc = 0.f;
#pragma unroll 4
    for (int d = 0; d < DIM; d += 4) {
        f32x4 w = *(const f32x4*)(wr + d);
        acc += srow[d] * w[0] + srow[d + 1] * w[1] + srow[d + 2] * w[2] + srow[d + 3] * w[3];
    }
    qf[s * DIM + e] = acc;
}

// ---------------- Kernel 2: KV = x @ [Wk|Wv]^T  (bf16 MFMA GEMM) ----------------
#define BM 128
#define BN 128
#define BK 32
#define ASTR 40  // padded LDS row stride (ushorts)

__device__ __forceinline__ u16x8 cvt8(const float* p) {
    f32x4 a = *(const f32x4*)p;
    f32x4 b = *(const f32x4*)(p + 4);
    u16x8 r;
    r[0] = f2bf(a[0]); r[1] = f2bf(a[1]); r[2] = f2bf(a[2]); r[3] = f2bf(a[3]);
    r[4] = f2bf(b[0]); r[5] = f2bf(b[1]); r[6] = f2bf(b[2]); r[7] = f2bf(b[3]);
    return r;
}

__global__ __launch_bounds__(256) void kv_gemm_kernel(const float* __restrict__ x,
                                                      const float* __restrict__ Wk,
                                                      const float* __restrict__ Wv,
                                                      u16* __restrict__ kv) {
    __shared__ u16 Alds[BM * ASTR];
    __shared__ u16 Blds[BM * ASTR];
    int nb = blockIdx.x;  // 0..3 -> output cols [nb*128, nb*128+128)
    int mb = blockIdx.y;  // 0..511
    const float* wsrc = (nb < 2) ? (Wk + (size_t)nb * BN * DIM) : (Wv + (size_t)(nb - 2) * BN * DIM);
    const float* asrc = x + (size_t)mb * BM * DIM;

    int tid = threadIdx.x;
    int srow = tid >> 1;
    int scol = (tid & 1) * 16;
    int lane = tid & 63;
    int wid = tid >> 6;
    int wr = wid >> 1, wc = wid & 1;

    f32x4 acc[4][4];
#pragma unroll
    for (int m = 0; m < 4; m++)
#pragma unroll
        for (int n = 0; n < 4; n++) acc[m][n] = (f32x4){0.f, 0.f, 0.f, 0.f};

    int k8 = (lane >> 4) * 8;   // k-offset within BK for this lane group (bijection k=8g+j)
    int fr = lane & 15;         // fragment row/col index

    for (int k0 = 0; k0 < DIM; k0 += BK) {
        const float* ap = asrc + (size_t)srow * DIM + k0 + scol;
        const float* bp = wsrc + (size_t)srow * DIM + k0 + scol;
        *(u16x8*)&Alds[srow * ASTR + scol]     = cvt8(ap);
        *(u16x8*)&Alds[srow * ASTR + scol + 8] = cvt8(ap + 8);
        *(u16x8*)&Blds[srow * ASTR + scol]     = cvt8(bp);
        *(u16x8*)&Blds[srow * ASTR + scol + 8] = cvt8(bp + 8);
        __syncthreads();

        s16x8 af[4], bfg[4];
#pragma unroll
        for (int m = 0; m < 4; m++)
            af[m] = *(const s16x8*)&Alds[(wr * 64 + m * 16 + fr) * ASTR + k8];
#pragma unroll
        for (int n = 0; n < 4; n++)
            bfg[n] = *(const s16x8*)&Blds[(wc * 64 + n * 16 + fr) * ASTR + k8];
#pragma unroll
        for (int m = 0; m < 4; m++)
#pragma unroll
            for (int n = 0; n < 4; n++)
                acc[m][n] = __builtin_amdgcn_mfma_f32_16x16x32_bf16(af[m], bfg[n], acc[m][n], 0, 0, 0);
        __syncthreads();
    }

    // C write: row = (lane>>4)*4 + q (M dim), col = lane&15 (N dim)
    int gmbase = mb * BM + wr * 64 + (lane >> 4) * 4;
    int gnbase = nb * BN + wc * 64 + fr;
#pragma unroll
    for (int m = 0; m < 4; m++) {
        int rbase = gmbase + m * 16;
#pragma unroll
        for (int n = 0; n < 4; n++) {
            int gc = gnbase + n * 16;
#pragma unroll
            for (int q = 0; q < 4; q++) {
                kv[(size_t)(rbase + q) * 512 + gc] = f2bf(acc[m][n][q]);
            }
        }
    }
}

// ---------------- Kernel 3: attention accumulate (partials) ----------------
#define GRP 8
__global__ __launch_bounds__(256) void attn_kernel(const u16* __restrict__ kv,
                                                   const float* __restrict__ qf,
                                                   const int* __restrict__ lens,
                                                   float* __restrict__ partials) {
    int b = blockIdx.y, chunk = blockIdx.x;
    int len = get_len(lens, b);
    int n0 = chunk * CHUNK;
    int n1 = min(n0 + CHUNK, len);
    int p = threadIdx.x;
    int h = p >> 5, s = p & 31;

    float qreg[DHEAD];
#pragma unroll
    for (int j = 0; j < DHEAD; j += 4) {
        f32x4 q4 = *(const f32x4*)(qf + s * DIM + h * DHEAD + j);
        qreg[j] = q4[0]; qreg[j + 1] = q4[1]; qreg[j + 2] = q4[2]; qreg[j + 3] = q4[3];
    }

    __shared__ float kvlds[GRP * 512];
    float denom = 0.f;
    float numer[DHEAD];
#pragma unroll
    for (int j = 0; j < DHEAD; j++) numer[j] = 0.f;

    for (int g0 = n0; g0 < n1; g0 += GRP) {
        // stage GRP rows of KV (bf16 -> fp32) : 4096 elems, 16 per thread
        {
            size_t base = ((size_t)b * NKEY + g0) * 512 + p * 16;
            u16x8 u0 = *(const u16x8*)&kv[base];
            u16x8 u1 = *(const u16x8*)&kv[base + 8];
            float* dst = kvlds + p * 16;
            f32x4 f0 = {bf2f(u0[0]), bf2f(u0[1]), bf2f(u0[2]), bf2f(u0[3])};
            f32x4 f1 = {bf2f(u0[4]), bf2f(u0[5]), bf2f(u0[6]), bf2f(u0[7])};
            f32x4 f2 = {bf2f(u1[0]), bf2f(u1[1]), bf2f(u1[2]), bf2f(u1[3])};
            f32x4 f3 = {bf2f(u1[4]), bf2f(u1[5]), bf2f(u1[6]), bf2f(u1[7])};
            *(f32x4*)(dst) = f0; *(f32x4*)(dst + 4) = f1;
            *(f32x4*)(dst + 8) = f2; *(f32x4*)(dst + 12) = f3;
        }
        __syncthreads();
        int gmax = min(GRP, n1 - g0);
        for (int r = 0; r < gmax; r++) {
            const float* krow = kvlds + r * 512 + h * DHEAD;
            float sc = 0.f;
#pragma unroll
            for (int j = 0; j < 8; j++) {
                f32x4 kk = *(const f32x4*)(krow + 4 * j);
                sc += qreg[4 * j] * kk[0] + qreg[4 * j + 1] * kk[1] +
                      qreg[4 * j + 2] * kk[2] + qreg[4 * j + 3] * kk[3];
            }
            float e = __expf(sc * SCALE);
            denom += e;
            const float* vrow = krow + 256;
#pragma unroll
            for (int j = 0; j < 8; j++) {
                f32x4 vv = *(const f32x4*)(vrow + 4 * j);
                numer[4 * j] += e * vv[0]; numer[4 * j + 1] += e * vv[1];
                numer[4 * j + 2] += e * vv[2]; numer[4 * j + 3] += e * vv[3];
            }
        }
        __syncthreads();
    }

    float* pb = partials + (size_t)(b * NCHUNK + chunk) * PART_STRIDE;
#pragma unroll
    for (int j = 0; j < DHEAD; j += 4) {
        f32x4 v = {numer[j], numer[j + 1], numer[j + 2], numer[j + 3]};
        *(f32x4*)&pb[p * DHEAD + j] = v;
    }
    pb[8192 + p] = denom;
}

// ---------------- Kernel 4: reduce partials -> O_pre = Q + numer/denom ----------------
__global__ __launch_bounds__(256) void reduce_kernel(const float* __restrict__ partials,
                                                     const float* __restrict__ qf,
                                                     const int* __restrict__ lens,
                                                     float* __restrict__ opre,
                                                     float* __restrict__ outlen) {
    int b = blockIdx.x;
    int p = threadIdx.x;
    int h = p >> 5, s = p & 31;
    float denom = 0.f;
    float num[DHEAD];
#pragma unroll
    for (int j = 0; j < DHEAD; j++) num[j] = 0.f;
    for (int c = 0; c < NCHUNK; c++) {
        const float* pb = partials + (size_t)(b * NCHUNK + c) * PART_STRIDE;
        denom += pb[8192 + p];
#pragma unroll
        for (int j = 0; j < DHEAD; j += 4) {
            f32x4 v = *(const f32x4*)&pb[p * DHEAD + j];
            num[j] += v[0]; num[j + 1] += v[1]; num[j + 2] += v[2]; num[j + 3] += v[3];
        }
    }
    float inv = 1.f / (denom + 1e-15f);
    size_t obase = ((size_t)b * SEEDS + s) * DIM + h * DHEAD;
#pragma unroll
    for (int j = 0; j < DHEAD; j++) {
        opre[obase + j] = qf[s * DIM + h * DHEAD + j] + num[j] * inv;
    }
    if (p == 0) outlen[b] = (float)min(SEEDS, get_len(lens, b));
}

// ---------------- Kernel 5: epilogue  out = (O + relu(O @ Wo^T)) * row_mask ----------------
__global__ __launch_bounds__(256) void epilogue_kernel(const float* __restrict__ opre,
                                                       const float* __restrict__ Wo,
                                                       const int* __restrict__ lens,
                                                       float* __restrict__ out) {
    int s = blockIdx.x, b = blockIdx.y;
    int d = threadIdx.x;
    size_t rbase = ((size_t)b * SEEDS + s) * DIM;
    if (s >= get_len(lens, b)) {
        out[rbase + d] = 0.f;
        return;
    }
    __shared__ float orow[DIM];
    orow[d] = opre[rbase + d];
    __syncthreads();
    const float* wrow = Wo + (size_t)d * DIM;
    float acc = 0.f;
#pragma unroll 4
    for (int e = 0; e < DIM; e += 4) {
        f32x4 w = *(const f32x4*)(wrow + e);
        acc += orow[e] * w[0] + orow[e + 1] * w[1] + orow[e + 2] * w[2] + orow[e + 3] * w[3];
    }
    out[rbase + d] = orow[d] + fmaxf(acc, 0.f);
}

extern "C" void kernel_launch(void* const* d_in, const int* in_sizes, int n_in,
                              void* d_out, int out_size, void* d_ws, size_t ws_size,
                              hipStream_t stream) {
    const float* x  = (const float*)d_in[0];
    const int* lens = (const int*)d_in[1];
    const float* S  = (const float*)d_in[2];
    const float* Wq = (const float*)d_in[3];
    const float* Wk = (const float*)d_in[4];
    const float* Wv = (const float*)d_in[5];
    const float* Wo = (const float*)d_in[6];
    float* out = (float*)d_out;

    char* ws = (char*)d_ws;
    float* qf       = (float*)ws;                                   // 32 KB
    float* opre     = (float*)(ws + 32768);                         // 1 MB
    float* partials = (float*)(ws + 32768 + 1048576);               // 17.3 MB
    u16*   kv       = (u16*)(ws + 32768 + 1048576 + 17301504);      // 67 MB

    qproj_kernel<<<dim3(SEEDS), 256, 0, stream>>>(S, Wq, qf);
    kv_gemm_kernel<<<dim3(4, 512), 256, 0, stream>>>(x, Wk, Wv, kv);
    attn_kernel<<<dim3(NCHUNK, BATCH), 256, 0, stream>>>(kv, qf, lens, partials);
    reduce_kernel<<<dim3(BATCH), 256, 0, stream>>>(partials, qf, lens, opre,
                                                   out + (size_t)BATCH * SEEDS * DIM);
    epilogue_kernel<<<dim3(SEEDS, BATCH), 256, 0, stream>>>(opre, Wo, lens, out);
}